// Round 4
// baseline (358.913 us; speedup 1.0000x reference)
//
#include <hip/hip_runtime.h>
#include <stdint.h>

// ---------------- problem constants ----------------
#define EMB   1024
#define NHEAD 16
#define CHD   64
#define NB    4
#define SEQ   2048
#define NTOK  (NB * SEQ)        // 8192
#define KDIM  1024

typedef __attribute__((ext_vector_type(8)))  short bf16x8;
typedef __attribute__((ext_vector_type(4)))  short short4v;
typedef __attribute__((ext_vector_type(4)))  float f32x4;
typedef __attribute__((ext_vector_type(16))) float f32x16;
typedef __attribute__((ext_vector_type(4)))  float float4v;

// float -> bf16 (RNE), bit pattern in a short
__device__ __forceinline__ short f2bf(float f) {
    unsigned int u = __float_as_uint(f);
    u += 0x7fffu + ((u >> 16) & 1u);
    return (short)(u >> 16);
}

// async global->LDS, 16B per lane; lds base must be wave-uniform, lane i lands at base + i*16B
__device__ __forceinline__ void async16(const short* g, short* l) {
    __builtin_amdgcn_global_load_lds((__attribute__((address_space(1))) void const*)g,
                                     (__attribute__((address_space(3))) void*)l, 16, 0, 0);
}

// ---------------- fp32 -> bf16 convert, all 5 tensors in one launch ----------------
__global__ __launch_bounds__(256) void cvt_all(const float* __restrict__ x,
                                               const float* __restrict__ Wq,
                                               const float* __restrict__ Wk,
                                               const float* __restrict__ Wv,
                                               const float* __restrict__ Wo,
                                               short* __restrict__ xb,
                                               short* __restrict__ Wqb,
                                               short* __restrict__ Wkb,
                                               short* __restrict__ Wvb,
                                               short* __restrict__ Wob) {
    int bid = blockIdx.x;
    const float* src;
    short* dst;
    int idx;
    if (bid < 8192) {
        src = x; dst = xb; idx = bid * 256 + threadIdx.x;
    } else {
        int w  = (bid - 8192) >> 10;
        int lb = (bid - 8192) & 1023;
        src = (w == 0) ? Wq : (w == 1) ? Wk : (w == 2) ? Wv : Wo;
        dst = (w == 0) ? Wqb : (w == 1) ? Wkb : (w == 2) ? Wvb : Wob;
        idx = lb * 256 + threadIdx.x;
    }
    float4v v = ((const float4v*)src)[idx];
    short4v s;
    s.x = f2bf(v.x); s.y = f2bf(v.y); s.z = f2bf(v.z); s.w = f2bf(v.w);
    ((short4v*)dst)[idx] = s;
}

// ---------------- shared GEMM core ----------------
__device__ __forceinline__ void gemm_core(const short* __restrict__ Atile,
                                          const short* __restrict__ Btile,
                                          short* As, short* Bs, f32x4 acc[4][4]) {
    const int tid  = threadIdx.x;
    const int wave = tid >> 6, lane = tid & 63;
    const int quad = lane >> 4, l16 = lane & 15;
    const int wm = (wave >> 1) * 64, wn = (wave & 1) * 64;
    const int srow = lane >> 2;
    const int scol = (lane & 3) * 8;

    for (int k0 = 0; k0 < KDIM; k0 += 32) {
        __syncthreads();
#pragma unroll
        for (int c = 0; c < 2; ++c) {
            int chunk = wave * 2 + c;
            int row = chunk * 16 + srow;
            async16(Atile + (size_t)row * KDIM + k0 + scol, As + chunk * 512);
            async16(Btile + (size_t)row * KDIM + k0 + scol, Bs + chunk * 512);
        }
        __syncthreads();
        bf16x8 af[4], bfr[4];
#pragma unroll
        for (int i = 0; i < 4; ++i)
            af[i] = *(const bf16x8*)&As[(wm + i * 16 + l16) * 32 + quad * 8];
#pragma unroll
        for (int j = 0; j < 4; ++j)
            bfr[j] = *(const bf16x8*)&Bs[(wn + j * 16 + l16) * 32 + quad * 8];
#pragma unroll
        for (int i = 0; i < 4; ++i)
#pragma unroll
            for (int j = 0; j < 4; ++j)
                acc[i][j] = __builtin_amdgcn_mfma_f32_16x16x32_bf16(af[i], bfr[j], acc[i][j], 0, 0, 0);
    }
}

// ---------------- QKV projection ----------------
// Q output pre-scaled by 0.125*log2(e) so attention uses raw exp2.
// V blocks use SWAPPED operands (A=Wv, B=x) so the V^T store is lane-contiguous.
#define QSCALE 0.1803368801111204f
__global__ __launch_bounds__(256) void qkv_gemm(const short* __restrict__ xb,
                                                const short* __restrict__ Wqb,
                                                const short* __restrict__ Wkb,
                                                const short* __restrict__ Wvb,
                                                const float* __restrict__ bq,
                                                const float* __restrict__ bk,
                                                const float* __restrict__ bv,
                                                short* __restrict__ Qb,
                                                short* __restrict__ Kb,
                                                short* __restrict__ Vtb) {
    __shared__ short As[128 * 32], Bs[128 * 32];
    const int bm = blockIdx.x, bn = blockIdx.y;
    const int which = bn >> 3;            // 0=Q 1=K 2=V
    const int ew = (bn & 7) * 128;
    const short* W    = (which == 0) ? Wqb : (which == 1) ? Wkb : Wvb;
    const float* bias = (which == 0) ? bq  : (which == 1) ? bk  : bv;
    const float sc    = (which == 0) ? QSCALE : 1.0f;

    const short* Xt = xb + (size_t)bm * 128 * KDIM;
    const short* Wt = W + (size_t)ew * KDIM;
    const short* Ap = (which == 2) ? Wt : Xt;
    const short* Bp = (which == 2) ? Xt : Wt;

    f32x4 acc[4][4];
    const f32x4 z = {0.f, 0.f, 0.f, 0.f};
#pragma unroll
    for (int i = 0; i < 4; ++i)
#pragma unroll
        for (int j = 0; j < 4; ++j) acc[i][j] = z;

    gemm_core(Ap, Bp, As, Bs, acc);

    const int lane = threadIdx.x & 63, wave = threadIdx.x >> 6;
    const int quad = lane >> 4, l16 = lane & 15;
    const int wm = (wave >> 1) * 64, wn = (wave & 1) * 64;

    if (which == 2) {
#pragma unroll
        for (int i = 0; i < 4; ++i)
#pragma unroll
            for (int j = 0; j < 4; ++j)
#pragma unroll
                for (int r = 0; r < 4; ++r) {
                    int e = ew + wm + i * 16 + quad * 4 + r;
                    int token = bm * 128 + wn + j * 16 + l16;
                    int bb = token >> 11, nn = token & 2047;
                    int hh = e >> 6, cc = e & 63;
                    Vtb[(((size_t)bb * NHEAD + hh) * CHD + cc) * SEQ + nn] =
                        f2bf(acc[i][j][r] + bias[e]);
                }
    } else {
        short* dst = which ? Kb : Qb;
#pragma unroll
        for (int i = 0; i < 4; ++i)
#pragma unroll
            for (int j = 0; j < 4; ++j)
#pragma unroll
                for (int r = 0; r < 4; ++r) {
                    int token = bm * 128 + wm + i * 16 + quad * 4 + r;
                    int bb = token >> 11, nn = token & 2047;
                    int e = ew + wn + j * 16 + l16;
                    int hh = e >> 6, cc = e & 63;
                    dst[(((size_t)bb * NHEAD + hh) * SEQ + nn) * CHD + cc] =
                        f2bf((acc[i][j][r] + bias[e]) * sc);
                }
    }
}

// ---------------- flash attention, 32x32x16 MFMA, 64 q-rows/wave ----------------
// Block = 2 waves (128 thr), wave owns 64 q-rows (2 q-tiles of 32). Per kt (128 kv):
// S^T = K·Q^T as 4 kv-tiles x 2 q-tiles; each K-frag read feeds both q-tiles;
// each V-frag read feeds both q-tiles in PV. 32 b128 reads / 64 MFMAs per wave-kt.
// kv permutation pi: LDS row l=32T+w (w=r+4h+8t) holds global kv
// g = 32T + 16(t>>1) + 8h + 4(t&1) + 2(r>>1) + (r&1), chosen so the exp'd 32x32
// C-layout packs into the 32x32x16 A-layout as CONSECUTIVE acc-reg pairs.
// l summed over TRUNCATED P values (consistent normalization). XOR-swizzled units.
__global__ __launch_bounds__(128, 2) void attn(const short* __restrict__ Qb,
                                               const short* __restrict__ Kb,
                                               const short* __restrict__ Vtb,
                                               short* __restrict__ AOb) {
    __shared__ short Ks[16 * 512];      // 128 kv x 64 ch (pi-permuted rows, swizzled units)
    __shared__ short Vs[16 * 512];      // 64 ch x 128 kv (swizzled units)

    const int qt = blockIdx.x;          // 0..15
    const int bh = blockIdx.y;          // 0..63
    const int tid = threadIdx.x, wave = tid >> 6, lane = tid & 63;
    const int l31 = lane & 31, h = lane >> 5;

    const short* Kg = Kb  + (size_t)bh * SEQ * CHD;
    const short* Vg = Vtb + (size_t)bh * CHD * SEQ;

    // Q fragments (kt-invariant, registers): qf[g][c], B-operand n=l31, k=16c+8h+i
    bf16x8 qf[2][4];
#pragma unroll
    for (int g = 0; g < 2; ++g)
#pragma unroll
        for (int c = 0; c < 4; ++c)
            qf[g][c] = *(const bf16x8*)(Qb + ((size_t)bh * SEQ + qt * 128 + wave * 64 + g * 32 + l31) * CHD
                                        + c * 16 + h * 8);

    // staging offsets (lane-dependent, kt-invariant); wave handles chunks wave*8..wave*8+7
    int koff[8], voff[8];
#pragma unroll
    for (int cc = 0; cc < 8; ++cc) {
        int c = wave * 8 + cc;
        int l = c * 8 + (lane >> 3);
        int w = l & 31, r = w & 3, hh = (w >> 2) & 1, t = w >> 3, T = l >> 5;
        int gkv = 32 * T + 16 * (t >> 1) + 8 * hh + 4 * (t & 1) + 2 * (r >> 1) + (r & 1);
        koff[cc] = gkv * CHD + (((lane & 7) ^ (l & 7)) << 3);
        int ch = c * 4 + (lane >> 4);
        voff[cc] = ch * SEQ + (((lane & 15) ^ (ch & 15)) << 3);
    }

    // reader offsets (shorts)
    int kra[4];
#pragma unroll
    for (int c = 0; c < 4; ++c)
        kra[c] = l31 * 64 + ((((2 * c + h) ^ (l31 & 7))) << 3);
    int vra[2];
#pragma unroll
    for (int s = 0; s < 2; ++s)
        vra[s] = l31 * 128 + ((((2 * s + h) ^ (l31 & 15))) << 3);

    const f32x16 z16 = {0.f,0.f,0.f,0.f,0.f,0.f,0.f,0.f,0.f,0.f,0.f,0.f,0.f,0.f,0.f,0.f};
    f32x16 O[2][2];
    O[0][0] = z16; O[0][1] = z16; O[1][0] = z16; O[1][1] = z16;
    f32x4 ls[2];
    ls[0] = (f32x4){0.f,0.f,0.f,0.f}; ls[1] = (f32x4){0.f,0.f,0.f,0.f};

    const short* Kgp = Kg;
    const short* Vgp = Vg;

    for (int kt = 0; kt < 16; ++kt) {
        __syncthreads();   // previous iteration's frag reads done
#pragma unroll
        for (int cc = 0; cc < 8; ++cc) {
            int c = wave * 8 + cc;
            async16(Kgp + koff[cc], Ks + c * 512);
            async16(Vgp + voff[cc], Vs + c * 512);
        }
        Kgp += 128 * CHD;
        Vgp += 128;
        __syncthreads();   // staging drained

#pragma unroll
        for (int T = 0; T < 4; ++T) {
            // S^T tiles: kv rows 32T..32T+31 (LDS-row space) x 32 q, both q-tiles
            f32x16 s0, s1;
            {
                bf16x8 kf = *(const bf16x8*)(Ks + kra[0] + T * 2048);
                s0 = __builtin_amdgcn_mfma_f32_32x32x16_bf16(kf, qf[0][0], z16, 0, 0, 0);
                s1 = __builtin_amdgcn_mfma_f32_32x32x16_bf16(kf, qf[1][0], z16, 0, 0, 0);
            }
#pragma unroll
            for (int c = 1; c < 4; ++c) {
                bf16x8 kf = *(const bf16x8*)(Ks + kra[c] + T * 2048);
                s0 = __builtin_amdgcn_mfma_f32_32x32x16_bf16(kf, qf[0][c], s0, 0, 0, 0);
                s1 = __builtin_amdgcn_mfma_f32_32x32x16_bf16(kf, qf[1][c], s1, 0, 0, 0);
            }

            // exp2 + pack into PV A-frags (consecutive reg pairs) + truncated row-sum
            bf16x8 pf[2][2];
#pragma unroll
            for (int g = 0; g < 2; ++g) {
                const f32x16 sg = g ? s1 : s0;
#pragma unroll
                for (int sg2 = 0; sg2 < 2; ++sg2) {
                    unsigned u[8];
#pragma unroll
                    for (int e = 0; e < 8; ++e)
                        u[e] = __float_as_uint(__builtin_amdgcn_exp2f(sg[sg2 * 8 + e]));
                    union { int i[4]; bf16x8 v; } pk;
                    pk.i[0] = __builtin_amdgcn_perm(u[1], u[0], 0x07060302u);
                    pk.i[1] = __builtin_amdgcn_perm(u[3], u[2], 0x07060302u);
                    pk.i[2] = __builtin_amdgcn_perm(u[5], u[4], 0x07060302u);
                    pk.i[3] = __builtin_amdgcn_perm(u[7], u[6], 0x07060302u);
                    pf[g][sg2] = pk.v;
                    // consistent l: sum TRUNCATED bf16 values
                    ls[g][0] += __uint_as_float(u[0] & 0xffff0000u) + __uint_as_float(u[4] & 0xffff0000u);
                    ls[g][1] += __uint_as_float(u[1] & 0xffff0000u) + __uint_as_float(u[5] & 0xffff0000u);
                    ls[g][2] += __uint_as_float(u[2] & 0xffff0000u) + __uint_as_float(u[6] & 0xffff0000u);
                    ls[g][3] += __uint_as_float(u[3] & 0xffff0000u) + __uint_as_float(u[7] & 0xffff0000u);
                }
            }

            // PV: steps s = 2T + sg2; V-frag shared across both q-tiles
#pragma unroll
            for (int sg2 = 0; sg2 < 2; ++sg2) {
                int vo = (vra[sg2] ^ (T << 5));
#pragma unroll
                for (int ct = 0; ct < 2; ++ct) {
                    bf16x8 vf = *(const bf16x8*)(Vs + vo + ct * 4096);
                    O[0][ct] = __builtin_amdgcn_mfma_f32_32x32x16_bf16(pf[0][sg2], vf, O[0][ct], 0, 0, 0);
                    O[1][ct] = __builtin_amdgcn_mfma_f32_32x32x16_bf16(pf[1][sg2], vf, O[1][ct], 0, 0, 0);
                }
            }
        }
    }

    // epilogue: l per q-row (lane l31 holds q=l31's partial over its h-half; xor32 completes)
    float lt[2];
#pragma unroll
    for (int g = 0; g < 2; ++g) {
        lt[g] = ls[g][0] + ls[g][1] + ls[g][2] + ls[g][3];
        lt[g] += __shfl_xor(lt[g], 32);
        lt[g] = 1.0f / lt[g];
    }

    const int b = bh >> 4, hd = bh & 15;
#pragma unroll
    for (int g = 0; g < 2; ++g)
#pragma unroll
        for (int reg = 0; reg < 16; ++reg) {
            int qr = (reg & 3) + 8 * (reg >> 2) + 4 * h;
            float li = __shfl(lt[g], qr);
            int n = qt * 128 + wave * 64 + g * 32 + qr;
#pragma unroll
            for (int ct = 0; ct < 2; ++ct) {
                int ccol = ct * 32 + l31;
                AOb[((size_t)b * SEQ + n) * EMB + hd * CHD + ccol] = f2bf(O[g][ct][reg] * li);
            }
        }
}

// ---------------- output projection ----------------
__global__ __launch_bounds__(256) void out_gemm(const short* __restrict__ AOb,
                                                const short* __restrict__ Wob,
                                                const float* __restrict__ bo,
                                                float* __restrict__ out) {
    __shared__ short As[128 * 32], Bs[128 * 32];
    const int bm = blockIdx.x, bn = blockIdx.y;

    f32x4 acc[4][4];
    const f32x4 z = {0.f, 0.f, 0.f, 0.f};
#pragma unroll
    for (int i = 0; i < 4; ++i)
#pragma unroll
        for (int j = 0; j < 4; ++j) acc[i][j] = z;

    gemm_core(AOb + (size_t)bm * 128 * KDIM, Wob + (size_t)bn * 128 * KDIM, As, Bs, acc);

    const int lane = threadIdx.x & 63, wave = threadIdx.x >> 6;
    const int quad = lane >> 4, l16 = lane & 15;
    const int wm = (wave >> 1) * 64, wn = (wave & 1) * 64;
#pragma unroll
    for (int i = 0; i < 4; ++i)
#pragma unroll
        for (int j = 0; j < 4; ++j)
#pragma unroll
            for (int r = 0; r < 4; ++r) {
                int token = bm * 128 + wm + i * 16 + quad * 4 + r;
                int e = bn * 128 + wn + j * 16 + l16;
                out[(size_t)token * EMB + e] = acc[i][j][r] + bo[e];
            }
}

// ---------------- launch ----------------
extern "C" void kernel_launch(void* const* d_in, const int* in_sizes, int n_in,
                              void* d_out, int out_size, void* d_ws, size_t ws_size,
                              hipStream_t stream) {
    const float* x  = (const float*)d_in[0];
    const float* Wq = (const float*)d_in[1];
    const float* bq = (const float*)d_in[2];
    const float* Wk = (const float*)d_in[3];
    const float* bk = (const float*)d_in[4];
    const float* Wv = (const float*)d_in[5];
    const float* bv = (const float*)d_in[6];
    const float* Wo = (const float*)d_in[7];
    const float* bo = (const float*)d_in[8];

    char* ws = (char*)d_ws;
    short* xb  = (short*)(ws + 0);                         // 16 MB
    short* Wqb = (short*)(ws + (size_t)16 * 1024 * 1024);  // 2 MB
    short* Wkb = (short*)(ws + (size_t)18 * 1024 * 1024);
    short* Wvb = (short*)(ws + (size_t)20 * 1024 * 1024);
    short* Wob = (short*)(ws + (size_t)22 * 1024 * 1024);
    short* Qb  = (short*)(ws + (size_t)24 * 1024 * 1024);  // 16 MB
    short* Kb  = (short*)(ws + (size_t)40 * 1024 * 1024);  // 16 MB
    short* Vtb = (short*)(ws + (size_t)56 * 1024 * 1024);  // 16 MB
    short* AOb = (short*)(ws + (size_t)72 * 1024 * 1024);  // 16 MB

    cvt_all<<<dim3(8192 + 4096), dim3(256), 0, stream>>>(x, Wq, Wk, Wv, Wo,
                                                         xb, Wqb, Wkb, Wvb, Wob);
    qkv_gemm<<<dim3(64, 24), dim3(256), 0, stream>>>(xb, Wqb, Wkb, Wvb, bq, bk, bv, Qb, Kb, Vtb);
    attn<<<dim3(16, 64), dim3(128), 0, stream>>>(Qb, Kb, Vtb, AOb);
    out_gemm<<<dim3(64, 8), dim3(256), 0, stream>>>(AOb, Wob, bo, (float*)d_out);
}

// Round 5
// 315.003 us; speedup vs baseline: 1.1394x; 1.1394x over previous
//
#include <hip/hip_runtime.h>
#include <stdint.h>

// ---------------- problem constants ----------------
#define EMB   1024
#define NHEAD 16
#define CHD   64
#define NB    4
#define SEQ   2048
#define NTOK  (NB * SEQ)        // 8192
#define KDIM  1024

typedef __attribute__((ext_vector_type(8)))  short bf16x8;
typedef __attribute__((ext_vector_type(4)))  short short4v;
typedef __attribute__((ext_vector_type(4)))  float f32x4;
typedef __attribute__((ext_vector_type(16))) float f32x16;
typedef __attribute__((ext_vector_type(4)))  float float4v;

// float -> bf16 (RNE), bit pattern in a short
__device__ __forceinline__ short f2bf(float f) {
    unsigned int u = __float_as_uint(f);
    u += 0x7fffu + ((u >> 16) & 1u);
    return (short)(u >> 16);
}

// async global->LDS, 16B per lane; lds base must be wave-uniform, lane i lands at base + i*16B
__device__ __forceinline__ void async16(const short* g, short* l) {
    __builtin_amdgcn_global_load_lds((__attribute__((address_space(1))) void const*)g,
                                     (__attribute__((address_space(3))) void*)l, 16, 0, 0);
}

// ---------------- fp32 -> bf16 convert, all 5 tensors in one launch ----------------
__global__ __launch_bounds__(256) void cvt_all(const float* __restrict__ x,
                                               const float* __restrict__ Wq,
                                               const float* __restrict__ Wk,
                                               const float* __restrict__ Wv,
                                               const float* __restrict__ Wo,
                                               short* __restrict__ xb,
                                               short* __restrict__ Wqb,
                                               short* __restrict__ Wkb,
                                               short* __restrict__ Wvb,
                                               short* __restrict__ Wob) {
    int bid = blockIdx.x;
    const float* src;
    short* dst;
    int idx;
    if (bid < 8192) {
        src = x; dst = xb; idx = bid * 256 + threadIdx.x;
    } else {
        int w  = (bid - 8192) >> 10;
        int lb = (bid - 8192) & 1023;
        src = (w == 0) ? Wq : (w == 1) ? Wk : (w == 2) ? Wv : Wo;
        dst = (w == 0) ? Wqb : (w == 1) ? Wkb : (w == 2) ? Wvb : Wob;
        idx = lb * 256 + threadIdx.x;
    }
    float4v v = ((const float4v*)src)[idx];
    short4v s;
    s.x = f2bf(v.x); s.y = f2bf(v.y); s.z = f2bf(v.z); s.w = f2bf(v.w);
    ((short4v*)dst)[idx] = s;
}

// ---------------- shared GEMM core ----------------
__device__ __forceinline__ void gemm_core(const short* __restrict__ Atile,
                                          const short* __restrict__ Btile,
                                          short* As, short* Bs, f32x4 acc[4][4]) {
    const int tid  = threadIdx.x;
    const int wave = tid >> 6, lane = tid & 63;
    const int quad = lane >> 4, l16 = lane & 15;
    const int wm = (wave >> 1) * 64, wn = (wave & 1) * 64;
    const int srow = lane >> 2;
    const int scol = (lane & 3) * 8;

    for (int k0 = 0; k0 < KDIM; k0 += 32) {
        __syncthreads();
#pragma unroll
        for (int c = 0; c < 2; ++c) {
            int chunk = wave * 2 + c;
            int row = chunk * 16 + srow;
            async16(Atile + (size_t)row * KDIM + k0 + scol, As + chunk * 512);
            async16(Btile + (size_t)row * KDIM + k0 + scol, Bs + chunk * 512);
        }
        __syncthreads();
        bf16x8 af[4], bfr[4];
#pragma unroll
        for (int i = 0; i < 4; ++i)
            af[i] = *(const bf16x8*)&As[(wm + i * 16 + l16) * 32 + quad * 8];
#pragma unroll
        for (int j = 0; j < 4; ++j)
            bfr[j] = *(const bf16x8*)&Bs[(wn + j * 16 + l16) * 32 + quad * 8];
#pragma unroll
        for (int i = 0; i < 4; ++i)
#pragma unroll
            for (int j = 0; j < 4; ++j)
                acc[i][j] = __builtin_amdgcn_mfma_f32_16x16x32_bf16(af[i], bfr[j], acc[i][j], 0, 0, 0);
    }
}

// ---------------- QKV projection ----------------
// Q output pre-scaled by 0.125*log2(e) so attention uses raw exp2.
// V blocks use SWAPPED operands (A=Wv, B=x) so the V^T store is lane-contiguous.
#define QSCALE 0.1803368801111204f
__global__ __launch_bounds__(256) void qkv_gemm(const short* __restrict__ xb,
                                                const short* __restrict__ Wqb,
                                                const short* __restrict__ Wkb,
                                                const short* __restrict__ Wvb,
                                                const float* __restrict__ bq,
                                                const float* __restrict__ bk,
                                                const float* __restrict__ bv,
                                                short* __restrict__ Qb,
                                                short* __restrict__ Kb,
                                                short* __restrict__ Vtb) {
    __shared__ short As[128 * 32], Bs[128 * 32];
    const int bm = blockIdx.x, bn = blockIdx.y;
    const int which = bn >> 3;            // 0=Q 1=K 2=V
    const int ew = (bn & 7) * 128;
    const short* W    = (which == 0) ? Wqb : (which == 1) ? Wkb : Wvb;
    const float* bias = (which == 0) ? bq  : (which == 1) ? bk  : bv;
    const float sc    = (which == 0) ? QSCALE : 1.0f;

    const short* Xt = xb + (size_t)bm * 128 * KDIM;
    const short* Wt = W + (size_t)ew * KDIM;
    const short* Ap = (which == 2) ? Wt : Xt;
    const short* Bp = (which == 2) ? Xt : Wt;

    f32x4 acc[4][4];
    const f32x4 z = {0.f, 0.f, 0.f, 0.f};
#pragma unroll
    for (int i = 0; i < 4; ++i)
#pragma unroll
        for (int j = 0; j < 4; ++j) acc[i][j] = z;

    gemm_core(Ap, Bp, As, Bs, acc);

    const int lane = threadIdx.x & 63, wave = threadIdx.x >> 6;
    const int quad = lane >> 4, l16 = lane & 15;
    const int wm = (wave >> 1) * 64, wn = (wave & 1) * 64;

    if (which == 2) {
#pragma unroll
        for (int i = 0; i < 4; ++i)
#pragma unroll
            for (int j = 0; j < 4; ++j)
#pragma unroll
                for (int r = 0; r < 4; ++r) {
                    int e = ew + wm + i * 16 + quad * 4 + r;
                    int token = bm * 128 + wn + j * 16 + l16;
                    int bb = token >> 11, nn = token & 2047;
                    int hh = e >> 6, cc = e & 63;
                    Vtb[(((size_t)bb * NHEAD + hh) * CHD + cc) * SEQ + nn] =
                        f2bf(acc[i][j][r] + bias[e]);
                }
    } else {
        short* dst = which ? Kb : Qb;
#pragma unroll
        for (int i = 0; i < 4; ++i)
#pragma unroll
            for (int j = 0; j < 4; ++j)
#pragma unroll
                for (int r = 0; r < 4; ++r) {
                    int token = bm * 128 + wm + i * 16 + quad * 4 + r;
                    int bb = token >> 11, nn = token & 2047;
                    int e = ew + wn + j * 16 + l16;
                    int hh = e >> 6, cc = e & 63;
                    dst[(((size_t)bb * NHEAD + hh) * SEQ + nn) * CHD + cc] =
                        f2bf((acc[i][j][r] + bias[e]) * sc);
                }
    }
}

// ---------------- flash attention, 32x32x16 MFMA, 64 q-rows/wave ----------------
// Identical math to R4 (verified absmax 1.46e-3); resourcing fixed:
// launch_bounds(128,1) -> full 512-reg budget (R4's (128,2) split 128 arch + 128 acc
// and spilled ~150 MB of scratch traffic / dispatch). ls reduced to 2 scalars
// (a lane's 16 C-regs all belong to one q-column).
__global__ __launch_bounds__(128, 1) void attn(const short* __restrict__ Qb,
                                               const short* __restrict__ Kb,
                                               const short* __restrict__ Vtb,
                                               short* __restrict__ AOb) {
    __shared__ short Ks[16 * 512];      // 128 kv x 64 ch (pi-permuted rows, swizzled units)
    __shared__ short Vs[16 * 512];      // 64 ch x 128 kv (swizzled units)

    const int qt = blockIdx.x;          // 0..15
    const int bh = blockIdx.y;          // 0..63
    const int tid = threadIdx.x, wave = tid >> 6, lane = tid & 63;
    const int l31 = lane & 31, h = lane >> 5;

    const short* Kg = Kb  + (size_t)bh * SEQ * CHD;
    const short* Vg = Vtb + (size_t)bh * CHD * SEQ;

    // Q fragments (kt-invariant, registers): qf[g][c], B-operand n=l31, k=16c+8h+i
    bf16x8 qf[2][4];
#pragma unroll
    for (int g = 0; g < 2; ++g)
#pragma unroll
        for (int c = 0; c < 4; ++c)
            qf[g][c] = *(const bf16x8*)(Qb + ((size_t)bh * SEQ + qt * 128 + wave * 64 + g * 32 + l31) * CHD
                                        + c * 16 + h * 8);

    // staging offsets (lane-dependent, kt-invariant); wave handles chunks wave*8..wave*8+7
    int koff[8], voff[8];
#pragma unroll
    for (int cc = 0; cc < 8; ++cc) {
        int c = wave * 8 + cc;
        int l = c * 8 + (lane >> 3);
        int w = l & 31, r = w & 3, hh = (w >> 2) & 1, t = w >> 3, T = l >> 5;
        int gkv = 32 * T + 16 * (t >> 1) + 8 * hh + 4 * (t & 1) + 2 * (r >> 1) + (r & 1);
        koff[cc] = gkv * CHD + (((lane & 7) ^ (l & 7)) << 3);
        int ch = c * 4 + (lane >> 4);
        voff[cc] = ch * SEQ + (((lane & 15) ^ (ch & 15)) << 3);
    }

    // reader offsets (shorts)
    int kra[4];
#pragma unroll
    for (int c = 0; c < 4; ++c)
        kra[c] = l31 * 64 + ((((2 * c + h) ^ (l31 & 7))) << 3);
    int vra[2];
#pragma unroll
    for (int s = 0; s < 2; ++s)
        vra[s] = l31 * 128 + ((((2 * s + h) ^ (l31 & 15))) << 3);

    const f32x16 z16 = {0.f,0.f,0.f,0.f,0.f,0.f,0.f,0.f,0.f,0.f,0.f,0.f,0.f,0.f,0.f,0.f};
    f32x16 O[2][2];
    O[0][0] = z16; O[0][1] = z16; O[1][0] = z16; O[1][1] = z16;
    float ls[2] = {0.f, 0.f};

    const short* Kgp = Kg;
    const short* Vgp = Vg;

    for (int kt = 0; kt < 16; ++kt) {
        __syncthreads();   // previous iteration's frag reads done
#pragma unroll
        for (int cc = 0; cc < 8; ++cc) {
            int c = wave * 8 + cc;
            async16(Kgp + koff[cc], Ks + c * 512);
            async16(Vgp + voff[cc], Vs + c * 512);
        }
        Kgp += 128 * CHD;
        Vgp += 128;
        __syncthreads();   // staging drained

#pragma unroll
        for (int T = 0; T < 4; ++T) {
            // S^T tiles: kv rows 32T..32T+31 (LDS-row space) x 32 q, both q-tiles
            f32x16 s0, s1;
            {
                bf16x8 kf = *(const bf16x8*)(Ks + kra[0] + T * 2048);
                s0 = __builtin_amdgcn_mfma_f32_32x32x16_bf16(kf, qf[0][0], z16, 0, 0, 0);
                s1 = __builtin_amdgcn_mfma_f32_32x32x16_bf16(kf, qf[1][0], z16, 0, 0, 0);
            }
#pragma unroll
            for (int c = 1; c < 4; ++c) {
                bf16x8 kf = *(const bf16x8*)(Ks + kra[c] + T * 2048);
                s0 = __builtin_amdgcn_mfma_f32_32x32x16_bf16(kf, qf[0][c], s0, 0, 0, 0);
                s1 = __builtin_amdgcn_mfma_f32_32x32x16_bf16(kf, qf[1][c], s1, 0, 0, 0);
            }

            // exp2 + pack into PV A-frags (consecutive reg pairs) + truncated row-sum
            bf16x8 pf[2][2];
#pragma unroll
            for (int g = 0; g < 2; ++g) {
                const f32x16 sg = g ? s1 : s0;
                float lacc = 0.f;
#pragma unroll
                for (int sg2 = 0; sg2 < 2; ++sg2) {
                    unsigned u[8];
#pragma unroll
                    for (int e = 0; e < 8; ++e)
                        u[e] = __float_as_uint(__builtin_amdgcn_exp2f(sg[sg2 * 8 + e]));
                    union { int i[4]; bf16x8 v; } pk;
                    pk.i[0] = __builtin_amdgcn_perm(u[1], u[0], 0x07060302u);
                    pk.i[1] = __builtin_amdgcn_perm(u[3], u[2], 0x07060302u);
                    pk.i[2] = __builtin_amdgcn_perm(u[5], u[4], 0x07060302u);
                    pk.i[3] = __builtin_amdgcn_perm(u[7], u[6], 0x07060302u);
                    pf[g][sg2] = pk.v;
                    // consistent l: sum TRUNCATED bf16 values (pairwise tree)
                    float a0 = __uint_as_float(u[0] & 0xffff0000u) + __uint_as_float(u[1] & 0xffff0000u);
                    float a1 = __uint_as_float(u[2] & 0xffff0000u) + __uint_as_float(u[3] & 0xffff0000u);
                    float a2 = __uint_as_float(u[4] & 0xffff0000u) + __uint_as_float(u[5] & 0xffff0000u);
                    float a3 = __uint_as_float(u[6] & 0xffff0000u) + __uint_as_float(u[7] & 0xffff0000u);
                    lacc += (a0 + a1) + (a2 + a3);
                }
                ls[g] += lacc;
            }

            // PV: steps s = 2T + sg2; V-frag shared across both q-tiles
#pragma unroll
            for (int sg2 = 0; sg2 < 2; ++sg2) {
                int vo = (vra[sg2] ^ (T << 5));
#pragma unroll
                for (int ct = 0; ct < 2; ++ct) {
                    bf16x8 vf = *(const bf16x8*)(Vs + vo + ct * 4096);
                    O[0][ct] = __builtin_amdgcn_mfma_f32_32x32x16_bf16(pf[0][sg2], vf, O[0][ct], 0, 0, 0);
                    O[1][ct] = __builtin_amdgcn_mfma_f32_32x32x16_bf16(pf[1][sg2], vf, O[1][ct], 0, 0, 0);
                }
            }
        }
    }

    // epilogue: lane l31 holds q=l31's partial row-sum over its h-half; xor32 completes
    float lt[2];
#pragma unroll
    for (int g = 0; g < 2; ++g) {
        lt[g] = ls[g] + __shfl_xor(ls[g], 32);
        lt[g] = 1.0f / lt[g];
    }

    const int b = bh >> 4, hd = bh & 15;
#pragma unroll
    for (int g = 0; g < 2; ++g)
#pragma unroll
        for (int reg = 0; reg < 16; ++reg) {
            int qr = (reg & 3) + 8 * (reg >> 2) + 4 * h;
            float li = __shfl(lt[g], qr);
            int n = qt * 128 + wave * 64 + g * 32 + qr;
#pragma unroll
            for (int ct = 0; ct < 2; ++ct) {
                int ccol = ct * 32 + l31;
                AOb[((size_t)b * SEQ + n) * EMB + hd * CHD + ccol] = f2bf(O[g][ct][reg] * li);
            }
        }
}

// ---------------- output projection ----------------
__global__ __launch_bounds__(256) void out_gemm(const short* __restrict__ AOb,
                                                const short* __restrict__ Wob,
                                                const float* __restrict__ bo,
                                                float* __restrict__ out) {
    __shared__ short As[128 * 32], Bs[128 * 32];
    const int bm = blockIdx.x, bn = blockIdx.y;

    f32x4 acc[4][4];
    const f32x4 z = {0.f, 0.f, 0.f, 0.f};
#pragma unroll
    for (int i = 0; i < 4; ++i)
#pragma unroll
        for (int j = 0; j < 4; ++j) acc[i][j] = z;

    gemm_core(AOb + (size_t)bm * 128 * KDIM, Wob + (size_t)bn * 128 * KDIM, As, Bs, acc);

    const int lane = threadIdx.x & 63, wave = threadIdx.x >> 6;
    const int quad = lane >> 4, l16 = lane & 15;
    const int wm = (wave >> 1) * 64, wn = (wave & 1) * 64;
#pragma unroll
    for (int i = 0; i < 4; ++i)
#pragma unroll
        for (int j = 0; j < 4; ++j)
#pragma unroll
            for (int r = 0; r < 4; ++r) {
                int token = bm * 128 + wm + i * 16 + quad * 4 + r;
                int e = bn * 128 + wn + j * 16 + l16;
                out[(size_t)token * EMB + e] = acc[i][j][r] + bo[e];
            }
}

// ---------------- launch ----------------
extern "C" void kernel_launch(void* const* d_in, const int* in_sizes, int n_in,
                              void* d_out, int out_size, void* d_ws, size_t ws_size,
                              hipStream_t stream) {
    const float* x  = (const float*)d_in[0];
    const float* Wq = (const float*)d_in[1];
    const float* bq = (const float*)d_in[2];
    const float* Wk = (const float*)d_in[3];
    const float* bk = (const float*)d_in[4];
    const float* Wv = (const float*)d_in[5];
    const float* bv = (const float*)d_in[6];
    const float* Wo = (const float*)d_in[7];
    const float* bo = (const float*)d_in[8];

    char* ws = (char*)d_ws;
    short* xb  = (short*)(ws + 0);                         // 16 MB
    short* Wqb = (short*)(ws + (size_t)16 * 1024 * 1024);  // 2 MB
    short* Wkb = (short*)(ws + (size_t)18 * 1024 * 1024);
    short* Wvb = (short*)(ws + (size_t)20 * 1024 * 1024);
    short* Wob = (short*)(ws + (size_t)22 * 1024 * 1024);
    short* Qb  = (short*)(ws + (size_t)24 * 1024 * 1024);  // 16 MB
    short* Kb  = (short*)(ws + (size_t)40 * 1024 * 1024);  // 16 MB
    short* Vtb = (short*)(ws + (size_t)56 * 1024 * 1024);  // 16 MB
    short* AOb = (short*)(ws + (size_t)72 * 1024 * 1024);  // 16 MB

    cvt_all<<<dim3(8192 + 4096), dim3(256), 0, stream>>>(x, Wq, Wk, Wv, Wo,
                                                         xb, Wqb, Wkb, Wvb, Wob);
    qkv_gemm<<<dim3(64, 24), dim3(256), 0, stream>>>(xb, Wqb, Wkb, Wvb, bq, bk, bv, Qb, Kb, Vtb);
    attn<<<dim3(16, 64), dim3(128), 0, stream>>>(Qb, Kb, Vtb, AOb);
    out_gemm<<<dim3(64, 8), dim3(256), 0, stream>>>(AOb, Wob, bo, (float*)d_out);
}